// Round 10
// baseline (350.935 us; speedup 1.0000x reference)
//
#include <hip/hip_runtime.h>
#include <hip/hip_bf16.h>
#include <math.h>

#define BB 4
#define CC 128
#define HH 128
#define WW 128
#define HWs 16384
#define GG 8
#define OMCH 216

typedef __bf16 bf16_t;
typedef unsigned int u32;
typedef bf16_t bf16x2 __attribute__((ext_vector_type(2)));
typedef bf16_t bf16x4 __attribute__((ext_vector_type(4)));
typedef bf16_t bf16x8 __attribute__((ext_vector_type(8)));
typedef float f32x4 __attribute__((ext_vector_type(4)));

__device__ __forceinline__ float bf2f(u32 hword16) {   // hword16 = bf16 bits in low 16
    union { u32 u; float f; } t; t.u = hword16 << 16; return t.f;
}

// ---------------- prep: weight rearrange ----------------
// wpack1: W_off A-frags with x2 folded for c>=128 (feat_up*2 scale)
__global__ __launch_bounds__(256) void k_prep(const float* __restrict__ W_off,
                                              const float* __restrict__ W_om,
                                              const float* __restrict__ W_dcn,
                                              bf16_t* __restrict__ wpack1,
                                              bf16_t* __restrict__ wpack,
                                              bf16_t* __restrict__ wpdcn) {
    int idx = blockIdx.x * 256 + threadIdx.x;
    if (idx < 4096) {
        int j = idx;
        int lane = j & 63;
        int rest = j >> 6;       // 0..63
        int ot = rest & 7;
        int ks = rest >> 3;      // 0..7
        int o = ot * 16 + (lane & 15);
        int cbase = ks * 32 + ((lane >> 4) << 3);
        bf16x8 v;
        #pragma unroll
        for (int r = 0; r < 8; ++r) {
            float s = (cbase + r >= 128) ? 2.0f : 1.0f;
            v[r] = (bf16_t)(W_off[o * 256 + cbase + r] * s);
        }
        *((bf16x8*)wpack1 + j) = v;
    } else if (idx < 4096 + 36864) {
        int j = idx - 4096;
        int lane = j & 63;
        int rest = j >> 6;       // 0..575
        int ot = rest & 15;
        int ks = rest >> 4;      // 0..35
        int cblk = ks / 9, tap = ks % 9;
        int o = ot * 16 + (lane & 15);
        int cbase = cblk * 32 + ((lane >> 4) << 3);
        bf16x8 v;
        #pragma unroll
        for (int r = 0; r < 8; ++r) {
            float x = (o < OMCH) ? W_om[((o * 128 + cbase + r) * 9) + tap] : 0.0f;
            v[r] = (bf16_t)x;
        }
        *((bf16x8*)wpack + j) = v;
    } else if (idx < 4096 + 36864 + 20480) {
        int j = idx - 40960;
        int lane = j & 63;
        int rest = j >> 6;       // 0..319
        int ot = rest & 7;
        int gks = rest >> 3;     // 0..39
        int g = gks / 5, ks = gks % 5;
        int o = ot * 16 + (lane & 15);
        int Kbase = ks * 32 + ((lane >> 4) << 3);
        bf16x8 v;
        #pragma unroll
        for (int r = 0; r < 8; ++r) {
            int K = Kbase + r;
            float x = 0.0f;
            if (K < 144) {
                int tap = K >> 4, cpp = K & 15;
                x = W_dcn[((o * 128) + g * 16 + cpp) * 9 + tap];
            }
            v[r] = (bf16_t)x;
        }
        *((bf16x8*)wpdcn + j) = v;
    }
}

// ---------------- bilinear 2x upsample -> bf16, 2 px/thread ----------------
__global__ __launch_bounds__(256) void k_upsample(const float* __restrict__ fs,
                                                  bf16_t* __restrict__ fub) {
    int idx = blockIdx.x * 256 + threadIdx.x;   // over B*C*H*(W/2) = 4,194,304
    int i = idx & 63, y = (idx >> 6) & 127, bc = idx >> 13;
    int j = y >> 1;
    int ya, yb; float wya, wyb;
    if (y & 1) { ya = j; yb = (j < 63) ? j + 1 : 63; wya = 0.75f; wyb = 0.25f; }
    else       { ya = (j > 0) ? j - 1 : 0; yb = j;   wya = 0.25f; wyb = 0.75f; }
    int im1 = (i > 0) ? i - 1 : 0;
    int ip1 = (i < 63) ? i + 1 : 63;
    const float* p = fs + (size_t)bc * 4096;
    float am = p[ya * 64 + im1], a0 = p[ya * 64 + i], ap = p[ya * 64 + ip1];
    float bm = p[yb * 64 + im1], b0 = p[yb * 64 + i], bp = p[yb * 64 + ip1];
    float rm = wya * am + wyb * bm;
    float r0 = wya * a0 + wyb * b0;
    float rp = wya * ap + wyb * bp;
    bf16x2 o2;
    o2[0] = (bf16_t)(0.25f * rm + 0.75f * r0);
    o2[1] = (bf16_t)(0.75f * r0 + 0.25f * rp);
    *(bf16x2*)&fub[(size_t)idx * 2] = o2;
}

// ---------------- 1x1 conv via MFMA (bf16 in from fub, bf16 out) ----------------
#define X1LD 264
__global__ __launch_bounds__(256) void k_conv1m(const float* __restrict__ fl,
                                                const bf16_t* __restrict__ fub,
                                                const bf16_t* __restrict__ wp1,
                                                bf16_t* __restrict__ offs) {
    __shared__ __align__(16) bf16_t X[64][X1LD];
    int t = threadIdx.x, lane = t & 63, w = t >> 6;
    int b = blockIdx.x >> 8;
    int pos0 = (blockIdx.x & 255) << 6;
    f32x4 acc[2][4];
    #pragma unroll
    for (int i = 0; i < 2; ++i)
        #pragma unroll
        for (int j = 0; j < 4; ++j)
            acc[i][j] = (f32x4){0.f, 0.f, 0.f, 0.f};
    #pragma unroll 4
    for (int it = 0; it < 32; ++it) {
        int cp = it * 4 + w;
        int c = cp * 2;
        if (c < 128) {
            size_t gb = (size_t)(b * 128 + c) * HWs + pos0 + lane;
            X[lane][c] = (bf16_t)fl[gb];
            X[lane][c + 1] = (bf16_t)fl[gb + HWs];
        } else {
            size_t gb = (size_t)(b * 128 + (c - 128)) * HWs + pos0 + lane;
            X[lane][c] = fub[gb];          // x2 folded into weights
            X[lane][c + 1] = fub[gb + HWs];
        }
    }
    __syncthreads();
    #pragma unroll
    for (int ks = 0; ks < 8; ++ks) {
        bf16x8 af[2], bfr[4];
        const bf16x8* wp = (const bf16x8*)wp1 + ((ks * 8 + w * 2) * 64 + lane);
        af[0] = wp[0];
        af[1] = wp[64];
        #pragma unroll
        for (int pi = 0; pi < 4; ++pi)
            bfr[pi] = *(const bf16x8*)&X[pi * 16 + (lane & 15)][ks * 32 + ((lane >> 4) << 3)];
        #pragma unroll
        for (int oi = 0; oi < 2; ++oi)
            #pragma unroll
            for (int pi = 0; pi < 4; ++pi)
                acc[oi][pi] = __builtin_amdgcn_mfma_f32_16x16x32_bf16(af[oi], bfr[pi], acc[oi][pi], 0, 0, 0);
    }
    #pragma unroll
    for (int oi = 0; oi < 2; ++oi) {
        int obase = (w * 2 + oi) * 16 + ((lane >> 4) << 2);
        #pragma unroll
        for (int j = 0; j < 4; ++j) {
            int o = obase + j;
            size_t ob = (size_t)(b * 128 + o) * HWs + pos0 + (lane & 15);
            #pragma unroll
            for (int pi = 0; pi < 4; ++pi)
                offs[ob + pi * 16] = (bf16_t)acc[oi][pi][j];
        }
    }
}

// ---------------- 3x3 conv via MFMA (bf16 in, bf16 om out) ----------------
#define X3LD 40
__global__ __launch_bounds__(256) void k_conv3m(const bf16_t* __restrict__ A,
                                                const bf16_t* __restrict__ wpack,
                                                const float* __restrict__ bom,
                                                bf16_t* __restrict__ om) {
    __shared__ __align__(16) bf16_t Xs[3 * 66 * X3LD];
    int t = threadIdx.x;
    int lane = t & 63, w = t >> 6;
    int b = blockIdx.x >> 8;
    int pos0 = (blockIdx.x & 255) << 6;
    int y = pos0 >> 7, x0 = pos0 & 127;
    f32x4 acc[4][4];
    #pragma unroll
    for (int i = 0; i < 4; ++i)
        #pragma unroll
        for (int j = 0; j < 4; ++j)
            acc[i][j] = (f32x4){0.f, 0.f, 0.f, 0.f};

    for (int cblk = 0; cblk < 4; ++cblk) {
        __syncthreads();
        for (int id = t; id < 3168; id += 256) {
            int col = id % 66;
            int rest = id / 66;
            int dy = rest % 3;
            int cp = rest / 3;
            int gy = y - 1 + dy, gx = x0 - 1 + col;
            bf16_t v0 = (bf16_t)0.f, v1 = (bf16_t)0.f;
            if ((unsigned)gy < 128u && (unsigned)gx < 128u) {
                size_t gb = ((size_t)(b * 128 + cblk * 32 + cp * 2) * 128 + gy) * 128 + gx;
                v0 = A[gb];
                v1 = A[gb + HWs];
            }
            int le = (dy * 66 + col) * X3LD + cp * 2;
            Xs[le] = v0;
            Xs[le + 1] = v1;
        }
        __syncthreads();
        #pragma unroll
        for (int tap = 0; tap < 9; ++tap) {
            const int ky = tap / 3, kx = tap % 3;
            bf16x8 af[4], bfr[4];
            const bf16x8* wp = (const bf16x8*)wpack + ((size_t)((cblk * 9 + tap) * 16 + w * 4) * 64 + lane);
            #pragma unroll
            for (int oi = 0; oi < 4; ++oi) af[oi] = wp[oi * 64];
            #pragma unroll
            for (int pi = 0; pi < 4; ++pi) {
                int colb = pi * 16 + (lane & 15) + kx;
                bfr[pi] = *(const bf16x8*)&Xs[(ky * 66 + colb) * X3LD + ((lane >> 4) << 3)];
            }
            #pragma unroll
            for (int oi = 0; oi < 4; ++oi)
                #pragma unroll
                for (int pi = 0; pi < 4; ++pi)
                    acc[oi][pi] = __builtin_amdgcn_mfma_f32_16x16x32_bf16(af[oi], bfr[pi], acc[oi][pi], 0, 0, 0);
        }
    }
    #pragma unroll
    for (int oi = 0; oi < 4; ++oi) {
        int obase = (w * 4 + oi) * 16 + ((lane >> 4) << 2);
        #pragma unroll
        for (int j = 0; j < 4; ++j) {
            int o = obase + j;
            if (o < OMCH) {
                float bv = bom[o];
                size_t ob = (size_t)(b * OMCH + o) * HWs + pos0 + (lane & 15);
                #pragma unroll
                for (int pi = 0; pi < 4; ++pi) {
                    float v = acc[oi][pi][j] + bv;
                    if (o >= 144) v = 1.0f / (1.0f + expf(-v));
                    om[ob + pi * 16] = (bf16_t)v;
                }
            }
        }
    }
}

// ---------------- DCNv2 via MFMA + relu + residual ----------------
// 512 threads = 8 waves, 2 groups/barrier interval. Gather from bf16 fub via
// aligned-u32 pair loads (2 loads + alignbit per (ch,row)); om params bf16.
// Tail 2 units split into 4 half-units over waves 0-3 (crit path 3 -> 2.5).
__global__ __launch_bounds__(512, 4) void k_dcn(const bf16_t* __restrict__ fub,
                                                const bf16_t* __restrict__ om,
                                                const bf16_t* __restrict__ wpd,
                                                const float* __restrict__ bdcn,
                                                const float* __restrict__ fl,
                                                float* __restrict__ outp) {
    __shared__ __align__(16) bf16_t val[2][64][168];
    int t = threadIdx.x;
    int lane = t & 63, w = t >> 6;           // wave 0..7
    int b = blockIdx.x >> 8;
    int pos0 = (blockIdx.x & 255) << 6;
    int y = pos0 >> 7, x0 = pos0 & 127;
    f32x4 acc[4];
    #pragma unroll
    for (int j = 0; j < 4; ++j) acc[j] = (f32x4){0.f, 0.f, 0.f, 0.f};
    for (int id = t; id < 2 * 64 * 24; id += 512) {
        int bufg = id / 1536, r = id % 1536;
        val[bufg][r / 24][144 + (r % 24)] = (bf16_t)0.0f;
    }

    const bf16_t* omb = om + (size_t)b * OMCH * HWs;
    const bf16_t* fb  = fub + (size_t)b * 128 * HWs;
    size_t sp = (size_t)y * 128 + x0 + lane;

    const int u1gl = (w + 8) / 9, u1tap = (w + 8) % 9;
    const int u2tap = 7 + (w >> 1);          // waves 0..3, gl=1
    const int u2c0 = (w & 1) * 8;

    // gather nch channels [ch0, ch0+nch) of group g, tap -> val[gl][lane][tap*16+ch0..]
    auto process_range = [&](int gl, int g, int tap, float oy, float ox, float m,
                             int ch0, int nch) __attribute__((always_inline)) {
        int ky = tap / 3, kx = tap % 3;
        int x = x0 + lane;
        float py = (float)(y - 1 + ky) + oy;
        float px = (float)(x - 1 + kx) + ox;
        float fy0 = floorf(py), fx0 = floorf(px);
        float ly = py - fy0, lx = px - fx0;
        int y0 = (int)fy0, x0i = (int)fx0;
        float vy0 = ((unsigned)y0 < 128u) ? 1.0f : 0.0f;
        float vy1 = ((unsigned)(y0 + 1) < 128u) ? 1.0f : 0.0f;
        float vx0 = ((unsigned)x0i < 128u) ? 1.0f : 0.0f;
        float vx1 = ((unsigned)(x0i + 1) < 128u) ? 1.0f : 0.0f;
        int yc0 = min(max(y0, 0), 127), yc1 = min(max(y0 + 1, 0), 127);
        int xc0 = min(max(x0i, 0), 127), xc1 = min(max(x0i + 1, 0), 127);
        float pw00 = (1.0f - ly) * (1.0f - lx) * m * vy0 * vx0;
        float pw01 = (1.0f - ly) * lx * m * vy0 * vx1;
        float pw10 = ly * (1.0f - lx) * m * vy1 * vx0;
        float pw11 = ly * lx * m * vy1 * vx1;
        int xr = min(xc0, 126);
        int s0 = xc0 - xr, s1 = xc1 - xr;
        float ax = (s0 ? 0.0f : pw00) + (s1 ? 0.0f : pw01);
        float ay = (s0 ? pw00 : 0.0f) + (s1 ? pw01 : 0.0f);
        float bx = (s0 ? 0.0f : pw10) + (s1 ? 0.0f : pw11);
        float by = (s0 ? pw10 : 0.0f) + (s1 ? pw11 : 0.0f);
        int s = xr & 1;
        int e_lo = yc0 * 128 + xr - s;       // even -> 4B-aligned bf16 pair
        int e_hi = yc1 * 128 + xr - s;
        const bf16_t* bp = fb + (size_t)(g * 16) * HWs;
        for (int cb = 0; cb < nch; cb += 4) {
            u32 alo[4], ahi[4], blo[4], bhi[4];
            #pragma unroll
            for (int c = 0; c < 4; ++c) {
                const bf16_t* p = bp + (size_t)(ch0 + cb + c) * HWs;
                alo[c] = *(const u32*)(p + e_lo);
                ahi[c] = *(const u32*)(p + e_lo + 2);
                blo[c] = *(const u32*)(p + e_hi);
                bhi[c] = *(const u32*)(p + e_hi + 2);
            }
            bf16x4 ov;
            #pragma unroll
            for (int c = 0; c < 4; ++c) {
                u32 ca = s ? ((alo[c] >> 16) | (ahi[c] << 16)) : alo[c];
                u32 cbp = s ? ((blo[c] >> 16) | (bhi[c] << 16)) : blo[c];
                float v = ax * bf2f(ca & 0xffffu) + ay * bf2f(ca >> 16)
                        + bx * bf2f(cbp & 0xffffu) + by * bf2f(cbp >> 16);
                ov[c] = (bf16_t)v;
            }
            *(bf16x4*)&val[gl][lane][tap * 16 + ch0 + cb] = ov;
        }
    };

    // preload params for gc=0
    float oy0, ox0, m0, oy1, ox1, m1, oy2 = 0.f, ox2 = 0.f, m2 = 0.f;
    {
        int g0 = 0, u1g = u1gl, u2g = 1;
        oy0 = (float)omb[(size_t)(g0 * 18 + w * 2) * HWs + sp];
        ox0 = (float)omb[(size_t)(g0 * 18 + w * 2 + 1) * HWs + sp];
        m0  = (float)omb[(size_t)(144 + g0 * 9 + w) * HWs + sp];
        oy1 = (float)omb[(size_t)(u1g * 18 + u1tap * 2) * HWs + sp];
        ox1 = (float)omb[(size_t)(u1g * 18 + u1tap * 2 + 1) * HWs + sp];
        m1  = (float)omb[(size_t)(144 + u1g * 9 + u1tap) * HWs + sp];
        if (w < 4) {
            oy2 = (float)omb[(size_t)(u2g * 18 + u2tap * 2) * HWs + sp];
            ox2 = (float)omb[(size_t)(u2g * 18 + u2tap * 2 + 1) * HWs + sp];
            m2  = (float)omb[(size_t)(144 + u2g * 9 + u2tap) * HWs + sp];
        }
    }

    for (int gc = 0; gc < 4; ++gc) {
        process_range(0, gc * 2, w, oy0, ox0, m0, 0, 16);
        process_range(u1gl, gc * 2 + u1gl, u1tap, oy1, ox1, m1, 0, 16);
        if (w < 4) process_range(1, gc * 2 + 1, u2tap, oy2, ox2, m2, u2c0, 8);
        // prefetch next interval's params; latency hides under MFMA phase
        if (gc < 3) {
            int g0 = (gc + 1) * 2;
            int u1g = g0 + u1gl, u2g = g0 + 1;
            oy0 = (float)omb[(size_t)(g0 * 18 + w * 2) * HWs + sp];
            ox0 = (float)omb[(size_t)(g0 * 18 + w * 2 + 1) * HWs + sp];
            m0  = (float)omb[(size_t)(144 + g0 * 9 + w) * HWs + sp];
            oy1 = (float)omb[(size_t)(u1g * 18 + u1tap * 2) * HWs + sp];
            ox1 = (float)omb[(size_t)(u1g * 18 + u1tap * 2 + 1) * HWs + sp];
            m1  = (float)omb[(size_t)(144 + u1g * 9 + u1tap) * HWs + sp];
            if (w < 4) {
                oy2 = (float)omb[(size_t)(u2g * 18 + u2tap * 2) * HWs + sp];
                ox2 = (float)omb[(size_t)(u2g * 18 + u2tap * 2 + 1) * HWs + sp];
                m2  = (float)omb[(size_t)(144 + u2g * 9 + u2tap) * HWs + sp];
            }
        }
        __syncthreads();
        #pragma unroll
        for (int gl = 0; gl < 2; ++gl) {
            int g = gc * 2 + gl;
            #pragma unroll
            for (int ks = 0; ks < 5; ++ks) {
                bf16x8 af = *((const bf16x8*)wpd + (((g * 5 + ks) * 8 + w) * 64 + lane));
                #pragma unroll
                for (int pi = 0; pi < 4; ++pi) {
                    bf16x8 bfr = *(const bf16x8*)&val[gl][pi * 16 + (lane & 15)][ks * 32 + ((lane >> 4) << 3)];
                    acc[pi] = __builtin_amdgcn_mfma_f32_16x16x32_bf16(af, bfr, acc[pi], 0, 0, 0);
                }
            }
        }
        __syncthreads();
    }
    #pragma unroll
    for (int j = 0; j < 4; ++j) {
        int o = w * 16 + ((lane >> 4) << 2) + j;
        float bv = bdcn[o];
        size_t base = (size_t)(b * 128 + o) * HWs + pos0 + (lane & 15);
        #pragma unroll
        for (int pi = 0; pi < 4; ++pi) {
            float v = fmaxf(acc[pi][j] + bv, 0.0f) + fl[base + pi * 16];
            outp[base + pi * 16] = v;
        }
    }
}

extern "C" void kernel_launch(void* const* d_in, const int* in_sizes, int n_in,
                              void* d_out, int out_size, void* d_ws, size_t ws_size,
                              hipStream_t stream) {
    const float* feat_l = (const float*)d_in[0];
    const float* feat_s = (const float*)d_in[1];
    const float* W_off  = (const float*)d_in[2];
    const float* W_om   = (const float*)d_in[3];
    const float* b_om   = (const float*)d_in[4];
    const float* W_dcn  = (const float*)d_in[5];
    const float* b_dcn  = (const float*)d_in[6];
    float* out = (float*)d_out;
    float* ws = (float*)d_ws;

    bf16_t* fub    = (bf16_t*)ws;                     // 8,388,608 bf16 (16 MB)
    bf16_t* offs   = (bf16_t*)(ws + 4194304);         // 8,388,608 bf16 (16 MB)
    bf16_t* om     = (bf16_t*)(ws + 8388608);         // 14,155,776 bf16 (28 MB)
    bf16_t* wpack1 = (bf16_t*)(ws + 15466496);        // 32,768 bf16
    bf16_t* wpack  = (bf16_t*)(ws + 15482880);        // 294,912 bf16
    bf16_t* wpdcn  = (bf16_t*)(ws + 15630336);        // 163,840 bf16

    k_prep<<<240, 256, 0, stream>>>(W_off, W_om, W_dcn, wpack1, wpack, wpdcn);
    k_upsample<<<16384, 256, 0, stream>>>(feat_s, fub);
    k_conv1m<<<1024, 256, 0, stream>>>(feat_l, fub, wpack1, offs);
    k_conv3m<<<1024, 256, 0, stream>>>(offs, wpack, b_om, om);
    k_dcn<<<1024, 512, 0, stream>>>(fub, om, wpdcn, b_dcn, feat_l, out);
}